// Round 2
// baseline (120.874 us; speedup 1.0000x reference)
//
#include <hip/hip_runtime.h>

// DensityLoss: out[b,y,x] = loss[b,y,x] * (fg ? 10 : 1) / (H*W) / B
// fg = pixel covered by >= 1 of 64 half-open boxes (x1,y1,x2,y2) per batch.
// B=8, H=W=1024, N=64. pred_densities is unused by the math.
//
// R2: barrier-free, LDS-free formulation. One block per row (b,y block-
// uniform => box loads are scalar s_load, y-tests are wave-uniform branches,
// ~21 of 64 boxes survive per row on average). Each thread computes a 4-bit
// x-coverage mask for its float4 directly: ~130 VALU ops/thread, hidden
// under the 64 MB HBM stream. One float4 load + one float4 store per thread.
//
// Numerics: /2^20 then /8 are exact power-of-2 scalings; (loss*w)*0x1p-23f
// is bit-exact vs the reference (verified absmax=0 in R1 with same formula).

#define NBOX 64

__global__ __launch_bounds__(256) void density_loss_kernel(
    const float* __restrict__ loss,
    const int4*  __restrict__ bboxes,
    float*       __restrict__ out)
{
    const int row = blockIdx.x;          // b*1024 + y  (block-uniform)
    const int b   = row >> 10;
    const int y   = row & 1023;
    const int t   = threadIdx.x;
    const int px0 = t << 2;              // first pixel of my float4

    const int4* __restrict__ box = bboxes + b * NBOX;  // uniform address

    // 4-bit coverage mask for pixels px0..px0+3
    unsigned int m = 0u;
    for (int i = 0; i < NBOX; ++i) {
        const int4 bx = box[i];          // scalar load (uniform)
        if (y >= bx.y && y < bx.w) {     // wave-uniform y-test
            const int lo = max(bx.x, px0);
            const int hi = min(bx.z, px0 + 4);
            if (lo < hi)
                m |= ((1u << (hi - lo)) - 1u) << (lo - px0);
        }
    }

    const size_t base = (size_t)row << 10;
    const float4 l = reinterpret_cast<const float4*>(loss + base)[t];
    const float C = 0x1p-23f;            // 1/(H*W)/B, exact

    float4 o;
    o.x = (l.x * ((m & 1u) ? 10.0f : 1.0f)) * C;
    o.y = (l.y * ((m & 2u) ? 10.0f : 1.0f)) * C;
    o.z = (l.z * ((m & 4u) ? 10.0f : 1.0f)) * C;
    o.w = (l.w * ((m & 8u) ? 10.0f : 1.0f)) * C;
    reinterpret_cast<float4*>(out + base)[t] = o;
}

extern "C" void kernel_launch(void* const* d_in, const int* in_sizes, int n_in,
                              void* d_out, int out_size, void* d_ws, size_t ws_size,
                              hipStream_t stream) {
    const float* loss   = (const float*)d_in[0];
    // d_in[1] = pred_densities: unused by the reference math
    const int4*  bboxes = (const int4*)d_in[2];
    float*       out    = (float*)d_out;

    const int n_rows = 8 * 1024;  // B * H
    density_loss_kernel<<<dim3(n_rows), dim3(256), 0, stream>>>(loss, bboxes, out);
}

// Round 3
// 112.092 us; speedup vs baseline: 1.0784x; 1.0784x over previous
//
#include <hip/hip_runtime.h>

// DensityLoss: out[b,y,x] = loss[b,y,x] * (fg ? 10 : 1) / (H*W) / B
// fg = pixel covered by >= 1 of 64 half-open boxes (x1,y1,x2,y2) per batch.
// B=8, H=W=1024, N=64. pred_densities unused by the math.
//
// R3: two-kernel split.
//  A: build cov[8192][32] u32 row-coverage masks in d_ws (1 MB). One thread
//     per 32-pixel word => 16.8M box tests total (8x less than R2's
//     per-thread loop), boxes staged in LDS (broadcast reads).
//  B: pure stream: float4 loss load + 1 mask-word load (L2-resident) +
//     float4 store. No barriers, no LDS => fillBuffer-like BW (~6.5 TB/s).
//
// Numerics: (loss*w) * 0x1p-23f is bit-exact vs reference (absmax=0 in R1/R2).

#define NBOX 64

// ---- Kernel A: one thread per u32 coverage word (32 pixels) ----
__global__ __launch_bounds__(256) void build_masks_kernel(
    const int4* __restrict__ bboxes,
    unsigned int* __restrict__ cov)
{
    __shared__ int4 sbox[NBOX];
    const int t   = threadIdx.x;
    const int bid = blockIdx.x;            // 0..1023; block covers 8 rows
    const int b   = bid >> 7;              // batch (uniform: 8 | 1024)

    if (t < NBOX)
        sbox[t] = bboxes[b * NBOX + t];
    __syncthreads();

    const int row  = (bid << 3) + (t >> 5);   // global row (b*1024 + y)
    const int y    = row & 1023;
    const int word = t & 31;
    const int lo_w = word << 5;

    unsigned int m = 0u;
    #pragma unroll 8
    for (int i = 0; i < NBOX; ++i) {
        const int4 bx = sbox[i];
        if (y >= bx.y && y < bx.w) {
            const int lo = max(bx.x, lo_w);
            const int hi = min(bx.z, lo_w + 32);
            if (lo < hi) {
                const int len = hi - lo;
                const unsigned int bits =
                    (len >= 32) ? 0xFFFFFFFFu : ((1u << len) - 1u);
                m |= bits << (lo - lo_w);
            }
        }
    }
    cov[(bid << 8) + t] = m;               // == row*32 + word, coalesced
}

// ---- Kernel B: pure stream apply ----
__global__ __launch_bounds__(256) void apply_kernel(
    const float* __restrict__ loss,
    const unsigned int* __restrict__ cov,
    float* __restrict__ out)
{
    const int row = blockIdx.x;            // b*1024 + y
    const int t   = threadIdx.x;

    const unsigned int cv = cov[(row << 5) + (t >> 3)];  // 8 lanes share word
    const int sh = (t & 7) << 2;

    const size_t base = (size_t)row << 10;
    const float4 l = reinterpret_cast<const float4*>(loss + base)[t];
    const float C = 0x1p-23f;              // 1/(H*W)/B, exact

    float4 o;
    o.x = (l.x * (((cv >> (sh + 0)) & 1u) ? 10.0f : 1.0f)) * C;
    o.y = (l.y * (((cv >> (sh + 1)) & 1u) ? 10.0f : 1.0f)) * C;
    o.z = (l.z * (((cv >> (sh + 2)) & 1u) ? 10.0f : 1.0f)) * C;
    o.w = (l.w * (((cv >> (sh + 3)) & 1u) ? 10.0f : 1.0f)) * C;
    reinterpret_cast<float4*>(out + base)[t] = o;
}

extern "C" void kernel_launch(void* const* d_in, const int* in_sizes, int n_in,
                              void* d_out, int out_size, void* d_ws, size_t ws_size,
                              hipStream_t stream) {
    const float* loss   = (const float*)d_in[0];
    // d_in[1] = pred_densities: unused by the reference math
    const int4*  bboxes = (const int4*)d_in[2];
    float*       out    = (float*)d_out;
    unsigned int* cov   = (unsigned int*)d_ws;   // 8192*32*4 = 1 MB

    build_masks_kernel<<<dim3(1024), dim3(256), 0, stream>>>(bboxes, cov);
    apply_kernel<<<dim3(8192), dim3(256), 0, stream>>>(loss, cov, out);
}